// Round 6
// baseline (223.639 us; speedup 1.0000x reference)
//
#include <hip/hip_runtime.h>

// RegularizationLoss: out = (1/2e6) * sum over 4M consecutive 3x3 matrices M
// of ||M M^T - I||_F^2.  Input (2000000,6,3) f32 = 144 MB. Memory-bound.
//
// Fused single kernel, ONE 9 KB tile per wave (no main loop, no barriers):
//  - wave issues 9 unit-stride float4 loads (9 KB in flight), stages into a
//    wave-PRIVATE LDS region, one lgkmcnt(0) drain, computes 4 matrices/lane.
//  - 16 waves/CU resident -> ~70+ KB in flight per CU -> BW-bound, latency hidden
//    by wave turnover (R5 lesson: per-wave serial tile loops kill MLP).
//  - LDS reads at 9-float odd stride: bank permutation, free 2-way aliasing.
//  - last-block-done reduction in fixed index order -> bit-deterministic.

#define NTHR 256
#define NWAVES 4
#define WT_F4 576       // float4 per wave-tile (256 matrices, 9216 B)
#define WT_FLOATS 2304

__global__ __launch_bounds__(NTHR) void reg_loss_fused(
    const float4* __restrict__ in4,
    float* __restrict__ partial,        // d_ws + 1024
    unsigned int* __restrict__ counter, // d_ws + 0
    float* __restrict__ out,
    int ntiles, float invN) {
    __shared__ float lds[NWAVES][WT_FLOATS];
    __shared__ float wsum[NWAVES];
    __shared__ int is_last;

    const int t = threadIdx.x;
    const int lane = t & 63;
    const int wid = t >> 6;
    const int T = blockIdx.x * NWAVES + wid;   // one tile per wave
    float acc = 0.0f;

    if (T < ntiles) {  // wave-uniform
        const float4* gp = in4 + (size_t)T * WT_F4 + lane;
        float4 v[9];
        #pragma unroll
        for (int k = 0; k < 9; ++k) v[k] = gp[64 * k];   // 9 loads in flight
        #pragma unroll
        for (int k = 0; k < 9; ++k)
            *(float4*)&lds[wid][4 * (64 * k + lane)] = v[k];
        asm volatile("s_waitcnt lgkmcnt(0)" ::: "memory");
        __builtin_amdgcn_sched_barrier(0);

        #pragma unroll
        for (int j = 0; j < 4; ++j) {
            const float* M = &lds[wid][9 * (64 * j + lane)];
            float a00 = M[0]*M[0] + M[1]*M[1] + M[2]*M[2] - 1.0f;
            float a11 = M[3]*M[3] + M[4]*M[4] + M[5]*M[5] - 1.0f;
            float a22 = M[6]*M[6] + M[7]*M[7] + M[8]*M[8] - 1.0f;
            float a01 = M[0]*M[3] + M[1]*M[4] + M[2]*M[5];
            float a02 = M[0]*M[6] + M[1]*M[7] + M[2]*M[8];
            float a12 = M[3]*M[6] + M[4]*M[7] + M[5]*M[8];
            acc += a00*a00 + a11*a11 + a22*a22
                 + 2.0f * (a01*a01 + a02*a02 + a12*a12);
        }
    }

    // wave64 reduction -> per-block partial
    #pragma unroll
    for (int off = 32; off > 0; off >>= 1) acc += __shfl_down(acc, off, 64);
    if (lane == 0) wsum[wid] = acc;
    __syncthreads();
    if (t == 0) {
        float s = wsum[0] + wsum[1] + wsum[2] + wsum[3];
        __hip_atomic_store(&partial[blockIdx.x], s,
                           __ATOMIC_RELEASE, __HIP_MEMORY_SCOPE_AGENT);
        unsigned old = __hip_atomic_fetch_add(counter, 1u,
                           __ATOMIC_ACQ_REL, __HIP_MEMORY_SCOPE_AGENT);
        is_last = (old == (unsigned)(gridDim.x - 1)) ? 1 : 0;
    }
    __syncthreads();

    if (is_last) {  // block-uniform
        __threadfence();
        float a2 = 0.0f;
        const int nb = (int)gridDim.x;
        for (int i = t; i < nb; i += NTHR) {  // fixed order -> deterministic
            a2 += __hip_atomic_load(&partial[i],
                      __ATOMIC_RELAXED, __HIP_MEMORY_SCOPE_AGENT);
        }
        #pragma unroll
        for (int off = 32; off > 0; off >>= 1) a2 += __shfl_down(a2, off, 64);
        if (lane == 0) wsum[wid] = a2;
        __syncthreads();
        if (t == 0) out[0] = (wsum[0] + wsum[1] + wsum[2] + wsum[3]) * invN;
    }
}

extern "C" void kernel_launch(void* const* d_in, const int* in_sizes, int n_in,
                              void* d_out, int out_size, void* d_ws, size_t ws_size,
                              hipStream_t stream) {
    const float* in = (const float*)d_in[0];
    float* out = (float*)d_out;
    unsigned int* counter = (unsigned int*)d_ws;
    float* partial = (float*)((char*)d_ws + 1024);

    const int total_floats = in_sizes[0];          // 36,000,000
    const int nbatch = total_floats / 18;          // 2,000,000
    const int ntiles = total_floats / WT_FLOATS;   // 15,625 exact (no tail)
    const int nblocks = (ntiles + NWAVES - 1) / NWAVES;  // 3907

    (void)hipMemsetAsync(counter, 0, sizeof(unsigned int), stream);
    reg_loss_fused<<<nblocks, NTHR, 0, stream>>>(
        (const float4*)in, partial, counter, out, ntiles, 1.0f / (float)nbatch);
}

// Round 7
// 31.089 us; speedup vs baseline: 7.1935x; 7.1935x over previous
//
#include <hip/hip_runtime.h>

// RegularizationLoss: out = (1/2e6) * sum over 4M consecutive 3x3 matrices M
// of ||M M^T - I||_F^2.  Input (2000000,6,3) f32 = 144 MB. Memory-bound.
//
// R7: two kernels, NO atomics (R6 lesson: contended same-address agent-scope
// atomics ~100ns each serialized -> 3907 of them = 355us tail).
// Kernel 1: one 9 KB wave-private LDS tile per wave, no __syncthreads in the
//   data path. Each lane: 9 unit-stride float4 loads (all in flight) -> LDS ->
//   one lgkmcnt drain -> 4 matrices from LDS (9-float odd stride = bank-
//   conflict-free permutation). Per-block partial via plain store.
// Kernel 2: one block sums 3907 partials in fixed index order -> deterministic.

#define NTHR 256
#define NWAVES 4
#define WT_F4 576       // float4 per wave-tile (256 matrices, 9216 B)
#define WT_FLOATS 2304

__global__ __launch_bounds__(NTHR) void reg_loss_partial(
    const float4* __restrict__ in4,
    float* __restrict__ partial,
    int ntiles) {
    __shared__ float lds[NWAVES][WT_FLOATS];
    __shared__ float wsum[NWAVES];

    const int t = threadIdx.x;
    const int lane = t & 63;
    const int wid = t >> 6;
    const int T = blockIdx.x * NWAVES + wid;   // one tile per wave
    float acc = 0.0f;

    if (T < ntiles) {  // wave-uniform
        const float4* gp = in4 + (size_t)T * WT_F4 + lane;
        float4 v[9];
        #pragma unroll
        for (int k = 0; k < 9; ++k) v[k] = gp[64 * k];   // 9 loads in flight
        #pragma unroll
        for (int k = 0; k < 9; ++k)
            *(float4*)&lds[wid][4 * (64 * k + lane)] = v[k];
        asm volatile("s_waitcnt lgkmcnt(0)" ::: "memory");
        __builtin_amdgcn_sched_barrier(0);

        #pragma unroll
        for (int j = 0; j < 4; ++j) {
            const float* M = &lds[wid][9 * (64 * j + lane)];
            float a00 = M[0]*M[0] + M[1]*M[1] + M[2]*M[2] - 1.0f;
            float a11 = M[3]*M[3] + M[4]*M[4] + M[5]*M[5] - 1.0f;
            float a22 = M[6]*M[6] + M[7]*M[7] + M[8]*M[8] - 1.0f;
            float a01 = M[0]*M[3] + M[1]*M[4] + M[2]*M[5];
            float a02 = M[0]*M[6] + M[1]*M[7] + M[2]*M[8];
            float a12 = M[3]*M[6] + M[4]*M[7] + M[5]*M[8];
            acc += a00*a00 + a11*a11 + a22*a22
                 + 2.0f * (a01*a01 + a02*a02 + a12*a12);
        }
    }

    // wave64 reduction -> per-block partial (plain store, no atomics)
    #pragma unroll
    for (int off = 32; off > 0; off >>= 1) acc += __shfl_down(acc, off, 64);
    if (lane == 0) wsum[wid] = acc;
    __syncthreads();
    if (t == 0) {
        partial[blockIdx.x] = wsum[0] + wsum[1] + wsum[2] + wsum[3];
    }
}

__global__ __launch_bounds__(256) void reg_loss_final(
    const float* __restrict__ partial, float* __restrict__ out,
    int nb, float invN) {
    float acc = 0.0f;
    for (int i = threadIdx.x; i < nb; i += 256) acc += partial[i];
    #pragma unroll
    for (int off = 32; off > 0; off >>= 1) acc += __shfl_down(acc, off, 64);

    __shared__ float wsum[4];
    const int lane = threadIdx.x & 63;
    const int wid  = threadIdx.x >> 6;
    if (lane == 0) wsum[wid] = acc;
    __syncthreads();
    if (threadIdx.x == 0) {
        out[0] = (wsum[0] + wsum[1] + wsum[2] + wsum[3]) * invN;
    }
}

extern "C" void kernel_launch(void* const* d_in, const int* in_sizes, int n_in,
                              void* d_out, int out_size, void* d_ws, size_t ws_size,
                              hipStream_t stream) {
    const float* in = (const float*)d_in[0];
    float* out = (float*)d_out;
    float* partial = (float*)d_ws;

    const int total_floats = in_sizes[0];          // 36,000,000
    const int nbatch = total_floats / 18;          // 2,000,000
    const int ntiles = total_floats / WT_FLOATS;   // 15,625 exact (no tail)
    const int nblocks = (ntiles + NWAVES - 1) / NWAVES;  // 3907

    reg_loss_partial<<<nblocks, NTHR, 0, stream>>>((const float4*)in, partial, ntiles);
    reg_loss_final<<<1, 256, 0, stream>>>(partial, out, nblocks, 1.0f / (float)nbatch);
}

// Round 8
// 30.776 us; speedup vs baseline: 7.2667x; 1.0102x over previous
//
#include <hip/hip_runtime.h>

// RegularizationLoss: out = (1/2e6) * sum over 4M consecutive 3x3 matrices M
// of ||M M^T - I||_F^2.  Input (2000000,6,3) f32 = 144 MB. Memory-bound.
//
// R8: max-occupancy one-shot, NO LDS. Each lane loads 9 consecutive float4
// (144 B = exactly 4 matrices, lane-local -> zero redistribution), computes
// directly from registers. No LDS -> no occupancy cap -> 32 waves/CU, ~2x the
// outstanding loads of any prior round. One matrix-quad per lane, one shot.
// Two kernels, no atomics (R6: contended agent atomics ~91 ns each serialized).

#define NTHR 256

__global__ __launch_bounds__(NTHR) void reg_loss_partial(
    const float4* __restrict__ in4,
    float* __restrict__ partial,
    int nthreads_active) {
    const int t = threadIdx.x;
    const int gid = blockIdx.x * NTHR + t;
    float acc = 0.0f;

    if (gid < nthreads_active) {
        const float4* gp = in4 + (size_t)gid * 9;
        float4 v[9];
        #pragma unroll
        for (int k = 0; k < 9; ++k) v[k] = gp[k];   // 9 loads in flight, 144 B chunk

        float m[36];
        #pragma unroll
        for (int k = 0; k < 9; ++k) {
            m[4 * k + 0] = v[k].x;
            m[4 * k + 1] = v[k].y;
            m[4 * k + 2] = v[k].z;
            m[4 * k + 3] = v[k].w;
        }

        #pragma unroll
        for (int h = 0; h < 4; ++h) {
            const float* M = m + h * 9;
            float a00 = M[0]*M[0] + M[1]*M[1] + M[2]*M[2] - 1.0f;
            float a11 = M[3]*M[3] + M[4]*M[4] + M[5]*M[5] - 1.0f;
            float a22 = M[6]*M[6] + M[7]*M[7] + M[8]*M[8] - 1.0f;
            float a01 = M[0]*M[3] + M[1]*M[4] + M[2]*M[5];
            float a02 = M[0]*M[6] + M[1]*M[7] + M[2]*M[8];
            float a12 = M[3]*M[6] + M[4]*M[7] + M[5]*M[8];
            acc += a00*a00 + a11*a11 + a22*a22
                 + 2.0f * (a01*a01 + a02*a02 + a12*a12);
        }
    }

    // wave64 reduction -> per-block partial (plain store)
    #pragma unroll
    for (int off = 32; off > 0; off >>= 1) acc += __shfl_down(acc, off, 64);

    __shared__ float wsum[NTHR / 64];
    const int lane = t & 63;
    const int wid  = t >> 6;
    if (lane == 0) wsum[wid] = acc;
    __syncthreads();
    if (t == 0) {
        partial[blockIdx.x] = wsum[0] + wsum[1] + wsum[2] + wsum[3];
    }
}

__global__ __launch_bounds__(256) void reg_loss_final(
    const float* __restrict__ partial, float* __restrict__ out,
    int nb, float invN) {
    float acc = 0.0f;
    for (int i = threadIdx.x; i < nb; i += 256) acc += partial[i];
    #pragma unroll
    for (int off = 32; off > 0; off >>= 1) acc += __shfl_down(acc, off, 64);

    __shared__ float wsum[4];
    const int lane = threadIdx.x & 63;
    const int wid  = threadIdx.x >> 6;
    if (lane == 0) wsum[wid] = acc;
    __syncthreads();
    if (threadIdx.x == 0) {
        out[0] = (wsum[0] + wsum[1] + wsum[2] + wsum[3]) * invN;
    }
}

extern "C" void kernel_launch(void* const* d_in, const int* in_sizes, int n_in,
                              void* d_out, int out_size, void* d_ws, size_t ws_size,
                              hipStream_t stream) {
    const float* in = (const float*)d_in[0];
    float* out = (float*)d_out;
    float* partial = (float*)d_ws;

    const int total_floats = in_sizes[0];            // 36,000,000
    const int nbatch = total_floats / 18;            // 2,000,000
    const int nquads = total_floats / 36;            // 1,000,000 (4 matrices each)
    const int nblocks = (nquads + NTHR - 1) / NTHR;  // 3907

    reg_loss_partial<<<nblocks, NTHR, 0, stream>>>((const float4*)in, partial, nquads);
    reg_loss_final<<<1, 256, 0, stream>>>(partial, out, nblocks, 1.0f / (float)nbatch);
}